// Round 10
// baseline (463.650 us; speedup 1.0000x reference)
//
#include <hip/hip_runtime.h>
#include <hip/hip_bf16.h>

// (B, C2, H, W) = (4, 1024, 64, 64); CH=512, HID=128, P=4096
#define NB 4
#define LOG2E 1.4426950408889634f

typedef unsigned short u16;
typedef __attribute__((ext_vector_type(8))) short bf16x8;
typedef __attribute__((ext_vector_type(4))) float f32x4;

static __device__ __forceinline__ float bf2f(u16 u) {
    union { float f; unsigned v; } x; x.v = ((unsigned)u) << 16; return x.f;
}
static __device__ __forceinline__ u16 f2bf(float f) {
    unsigned v = __builtin_bit_cast(unsigned, f);
    return (u16)((v + 0x7FFFu + ((v >> 16) & 1u)) >> 16);
}
static __device__ __forceinline__ void gload_lds16(const u16* g, u16* l) {
    __builtin_amdgcn_global_load_lds(
        (const __attribute__((address_space(1))) unsigned*)(const void*)g,
        (__attribute__((address_space(3))) unsigned*)(void*)l, 16, 0, 0);
}

// ---------------- A0: W f32 -> bf16 ----------------
__global__ void k_wcvt(const float* __restrict__ Wq, const float* __restrict__ Wk,
                       u16* __restrict__ Wbq, u16* __restrict__ Wbk) {
    int i = blockIdx.x * 1024 + threadIdx.x;   // 65536
    Wbq[i] = f2bf(Wq[i]);
    Wbk[i] = f2bf(Wk[i]);
}

// ---- A1-fused: contiguous-p layout. Block = (sb, pseg of 1024p, cpart of 8ch). ----
__global__ __launch_bounds__(256) void k_cvtf(
        const float* __restrict__ L, const float* __restrict__ R,
        u16* __restrict__ Lb, u16* __restrict__ Rb,
        u16* __restrict__ web, float* __restrict__ sumsH, float* __restrict__ out) {
    __shared__ float pred[4][1024];
    int idx = blockIdx.x;
    int sb = idx & 7, pseg = (idx >> 3) & 3, cpart = idx >> 5;   // 8 x 4 x 64
    int side = sb & 1, b = sb >> 1;
    int osb = side * 4 + b;
    const float* src = (side ? R : L) + (size_t)b * 1024 * 4096;
    u16* lbbase = (side ? Rb : Lb) + (size_t)b * 512 * 4096;
    int tid = threadIdx.x, wv = tid >> 6, lane = tid & 63;
    int p0 = pseg * 1024;
    int cA = cpart * 8 + wv * 2;
#pragma unroll
    for (int s = 0; s < 4; s++) {
        int p = p0 + s * 256 + lane * 4;
        float4 sm = {0.f, 0.f, 0.f, 0.f};
#pragma unroll
        for (int cc = 0; cc < 2; cc++) {
            int c = cA + cc;
            float4 a = *reinterpret_cast<const float4*>(src + (size_t)c * 4096 + p);
            float4 t = *reinterpret_cast<const float4*>(src + (size_t)(512 + c) * 4096 + p);
            ushort4 ub;
            ub.x = f2bf(a.x); ub.y = f2bf(a.y); ub.z = f2bf(a.z); ub.w = f2bf(a.w);
            *reinterpret_cast<ushort4*>(lbbase + (size_t)c * 4096 + p) = ub;
            *reinterpret_cast<float4*>(out + ((size_t)osb * 1024 + c) * 4096 + p) = a;
            float4 e;
            e.x = exp2f((a.x - t.x) * LOG2E);
            e.y = exp2f((a.y - t.y) * LOG2E);
            e.z = exp2f((a.z - t.z) * LOG2E);
            e.w = exp2f((a.w - t.w) * LOG2E);
            sm.x += e.x; sm.y += e.y; sm.z += e.z; sm.w += e.w;
            ushort4 wb_;
            wb_.x = f2bf(t.x * e.x); wb_.y = f2bf(t.y * e.y);
            wb_.z = f2bf(t.z * e.z); wb_.w = f2bf(t.w * e.w);
            *reinterpret_cast<ushort4*>(web + ((size_t)osb * 512 + c) * 4096 + p) = wb_;
        }
        *reinterpret_cast<float4*>(&pred[wv][s * 256 + lane * 4]) = sm;
    }
    __syncthreads();
    {
        float4 t0 = *reinterpret_cast<const float4*>(&pred[0][tid * 4]);
        float4 t1 = *reinterpret_cast<const float4*>(&pred[1][tid * 4]);
        float4 t2 = *reinterpret_cast<const float4*>(&pred[2][tid * 4]);
        float4 t3 = *reinterpret_cast<const float4*>(&pred[3][tid * 4]);
        float4 tot;
        tot.x = (t0.x + t1.x) + (t2.x + t3.x);
        tot.y = (t0.y + t1.y) + (t2.y + t3.y);
        tot.z = (t0.z + t1.z) + (t2.z + t3.z);
        tot.w = (t0.w + t1.w) + (t2.w + t3.w);
        *reinterpret_cast<float4*>(
            sumsH + ((size_t)cpart * 8 + osb) * 4096 + p0 + tid * 4) = tot;
    }
}

// ---- A1b: reduce 64 channel-part sums -> hinv = 1/sum ----
__global__ __launch_bounds__(256) void k_hsum(const float* __restrict__ sumsH,
                                              float* __restrict__ hinv) {
    int i = blockIdx.x * 256 + threadIdx.x;
    float4 tot = {0.f, 0.f, 0.f, 0.f};
    for (int cp = 0; cp < 64; cp++) {
        float4 v = *reinterpret_cast<const float4*>(sumsH + (size_t)cp * 8 * 4096 + (size_t)i * 4);
        tot.x += v.x; tot.y += v.y; tot.z += v.z; tot.w += v.w;
    }
    float4 r = {1.0f / tot.x, 1.0f / tot.y, 1.0f / tot.z, 1.0f / tot.w};
    *reinterpret_cast<float4*>(hinv + (size_t)i * 4) = r;
}

// ------- A1 (fallback): f32 -> bf16 convert; copy q_orig -------
__global__ void k_cvt(const float* __restrict__ L, const float* __restrict__ R,
                      u16* __restrict__ Lb, u16* __restrict__ Rb, float* __restrict__ out) {
    int i = blockIdx.x * 256 + threadIdx.x;
    int pq = i & 1023;
    int c = (i >> 10) & 511;
    int b = (i >> 19) & 3;
    int side = i >> 21;
    const float* src = (side ? R : L) + ((long)(b * 1024 + c) << 12) + (pq << 2);
    float4 v = *reinterpret_cast<const float4*>(src);
    ushort4 u;
    u.x = f2bf(v.x); u.y = f2bf(v.y); u.z = f2bf(v.z); u.w = f2bf(v.w);
    *reinterpret_cast<ushort4*>((side ? Rb : Lb) + ((long)(b * 512 + c) << 12) + (pq << 2)) = u;
    *reinterpret_cast<float4*>(out + ((long)(side * 4 + b) * 1024 + c) * 4096 + (pq << 2)) = v;
}

// ---------------- A2: projections via MFMA. Out: pos-major bf16 [p][128] ----------------
__global__ __launch_bounds__(256) void k_proj(
        const u16* __restrict__ Lb, const u16* __restrict__ Rb,
        const u16* __restrict__ Wbq, const u16* __restrict__ Wbk,
        const float* __restrict__ bq, const float* __restrict__ bk,
        u16* __restrict__ QL, u16* __restrict__ KL,
        u16* __restrict__ QR, u16* __restrict__ KR) {
    __shared__ u16 XT[2][64 * 40];
    int pj = blockIdx.x & 15, pt = blockIdx.x >> 4;
    int ty = pj >> 2, b = pj & 3;
    const u16* src; const u16* Wb; const float* bias; u16* dst;
    if (ty == 0)      { src = Lb; Wb = Wbq; bias = bq; dst = QL; }
    else if (ty == 1) { src = Rb; Wb = Wbk; bias = bk; dst = KL; }
    else if (ty == 2) { src = Rb; Wb = Wbq; bias = bq; dst = QR; }
    else              { src = Lb; Wb = Wbk; bias = bk; dst = KR; }
    const u16* X = src + (long)b * 512 * 4096 + pt * 64;
    int tid = threadIdx.x;
    int wv = __builtin_amdgcn_readfirstlane(tid >> 6);
    int lane = tid & 63, g = lane >> 4, li = lane & 15;

    f32x4 acc[8];
#pragma unroll
    for (int ob = 0; ob < 8; ob++)
#pragma unroll
        for (int r = 0; r < 4; r++) acc[ob][r] = bias[ob * 16 + g * 4 + r];

    int c_r = tid >> 3, j = tid & 7;
    bf16x8 gx = *reinterpret_cast<const bf16x8*>(X + (long)c_r * 4096 + j * 8);
#pragma unroll
    for (int k = 0; k < 8; k++) XT[0][(j * 8 + k) * 40 + c_r] = (u16)gx[k];
    __syncthreads();

    for (int cc = 0; cc < 16; cc++) {
        int buf = cc & 1;
        bf16x8 gn;
        if (cc < 15)
            gn = *reinterpret_cast<const bf16x8*>(X + (long)(cc * 32 + 32 + c_r) * 4096 + j * 8);
        bf16x8 xb = *reinterpret_cast<const bf16x8*>(&XT[buf][(wv * 16 + li) * 40 + g * 8]);
#pragma unroll
        for (int ob = 0; ob < 8; ob++) {
            bf16x8 aw = *reinterpret_cast<const bf16x8*>(Wb + (long)(ob * 16 + li) * 512 + cc * 32 + g * 8);
            acc[ob] = __builtin_amdgcn_mfma_f32_16x16x32_bf16(aw, xb, acc[ob], 0, 0, 0);
        }
        if (cc < 15) {
#pragma unroll
            for (int k = 0; k < 8; k++) XT[buf ^ 1][(j * 8 + k) * 40 + c_r] = (u16)gn[k];
        }
        __syncthreads();
    }
    u16* d = dst + ((long)b * 4096 + pt * 64 + wv * 16 + li) * 128;
#pragma unroll
    for (int ob = 0; ob < 8; ob++) {
        uint2 w;
        w.x = (unsigned)f2bf(acc[ob][0]) | ((unsigned)f2bf(acc[ob][1]) << 16);
        w.y = (unsigned)f2bf(acc[ob][2]) | ((unsigned)f2bf(acc[ob][3]) << 16);
        *reinterpret_cast<uint2*>(d + ob * 16 + g * 4) = w;
    }
}

// ---- B1: P = exp(Q.K^T), 8KB tiles [qtile][ptile][64q][64p-swz].
//      Tri-buffered K staging, counted vmcnt. bdMask=7 -> XCD pin by bd. ----
__global__ __launch_bounds__(512, 2) void k_qk(
        const u16* __restrict__ QL, const u16* __restrict__ KL,
        const u16* __restrict__ QR, const u16* __restrict__ KR,
        u16* __restrict__ P, float* __restrict__ sums,
        int bd0, int bdMask, int bdShift) {
    __shared__ u16 Kl[3][8192];
    __shared__ u16 Ps[4096];
    __shared__ float sred[4][2][16];
    int bdl, qtile, ph0;
    if (bdMask == 3) {
        int xcd = (int)blockIdx.x & 7;
        bdl = xcd >> 1; ph0 = xcd & 1; qtile = (int)blockIdx.x >> 3;
    } else {
        bdl = (int)blockIdx.x & bdMask;
        int rest = (int)blockIdx.x >> bdShift;
        qtile = rest & 63; ph0 = rest >> 6;
    }
    int bd = bd0 + bdl, dir = bd & 1, b = bd >> 1;
    const u16* Qt = (dir ? QR : QL) + (size_t)b * 4096 * 128;
    const u16* Kt = (dir ? KR : KL) + (size_t)b * 4096 * 128;
    u16* Pbd = P + ((size_t)bdl << 24);
    int q0 = qtile * 64;
    int tid = threadIdx.x;
    int wv = __builtin_amdgcn_readfirstlane(tid >> 6);
    int lane = tid & 63, g = lane >> 4, li = lane & 15;
    int qt = wv >> 1, phw = wv & 1;

#define STAGE_K(BUF, PT)                                                                   \
    {                                                                                      \
        _Pragma("unroll") for (int r0 = 0; r0 < 2; r0++) {                                 \
            int o = r0 * 8192 + tid * 16;                                                  \
            int row = o >> 8, w = o & 255;                                                 \
            int sw = (w ^ ((row & 7) << 4)) >> 1;                                          \
            gload_lds16(Kt + (((size_t)((PT) * 64 + row)) << 7) + sw,                      \
                        &Kl[BUF][r0 * 4096 + wv * 512]);                                   \
        }                                                                                  \
    }

    bf16x8 qf[4];
#pragma unroll
    for (int hc = 0; hc < 4; hc++)
        qf[hc] = *reinterpret_cast<const bf16x8*>(
            Qt + (size_t)(q0 + qt * 16 + li) * 128 + hc * 32 + g * 8);
    float psum = 0.f;
    STAGE_K(0, ph0 * 32)
    STAGE_K(1, ph0 * 32 + 1)

    int cur = 0;
    for (int tt = 0; tt < 32; tt++) {
        int pt = ph0 * 32 + tt;
        if (tt == 0)       asm volatile("s_waitcnt vmcnt(2) lgkmcnt(0)\n\ts_barrier" ::: "memory");
        else if (tt == 1)  asm volatile("s_waitcnt vmcnt(3) lgkmcnt(0)\n\ts_barrier" ::: "memory");
        else if (tt == 31) asm volatile("s_waitcnt vmcnt(2) lgkmcnt(0)\n\ts_barrier" ::: "memory");
        else               asm volatile("s_waitcnt vmcnt(4) lgkmcnt(0)\n\ts_barrier" ::: "memory");
        if (tt < 30) {
            int stg = cur + 2; if (stg >= 3) stg -= 3;
            STAGE_K(stg, pt + 2)
        }
        f32x4 sv[2];
        sv[0] = (f32x4){0.f, 0.f, 0.f, 0.f};
        sv[1] = (f32x4){0.f, 0.f, 0.f, 0.f};
        __builtin_amdgcn_s_setprio(1);
#pragma unroll
        for (int ps = 0; ps < 2; ps++) {
            int row = phw * 32 + ps * 16 + li;
            unsigned rb = (unsigned)row * 256;
            unsigned sz = (unsigned)((row & 7) << 4);
#pragma unroll
            for (int hc = 0; hc < 4; hc++) {
                bf16x8 kf = *reinterpret_cast<const bf16x8*>(
                    (char*)Kl[cur] + rb + (((unsigned)(hc * 64 + g * 16)) ^ sz));
                sv[ps] = __builtin_amdgcn_mfma_f32_16x16x32_bf16(kf, qf[hc], sv[ps], 0, 0, 0);
            }
        }
        __builtin_amdgcn_s_setprio(0);
        int qrow = qt * 16 + li;
        unsigned qsz = (unsigned)((qrow & 7) << 4);
#pragma unroll
        for (int ps = 0; ps < 2; ps++) {
            float e0 = exp2f(sv[ps][0] * LOG2E);
            float e1 = exp2f(sv[ps][1] * LOG2E);
            float e2 = exp2f(sv[ps][2] * LOG2E);
            float e3 = exp2f(sv[ps][3] * LOG2E);
            psum += (e0 + e1) + (e2 + e3);
            uint2 pk;
            pk.x = (unsigned)f2bf(e0) | ((unsigned)f2bf(e1) << 16);
            pk.y = (unsigned)f2bf(e2) | ((unsigned)f2bf(e3) << 16);
            unsigned off = (unsigned)qrow * 128 +
                           (((unsigned)(phw * 64 + ps * 32 + g * 8)) ^ qsz);
            *reinterpret_cast<uint2*>((char*)Ps + off) = pk;
        }
        asm volatile("s_waitcnt lgkmcnt(0)\n\ts_barrier" ::: "memory");
        {
            uint4 d = *reinterpret_cast<const uint4*>((char*)Ps + tid * 16);
            *reinterpret_cast<uint4*>(
                Pbd + ((size_t)(qtile * 64 + pt) << 12) + tid * 8) = d;
        }
        cur = (cur + 1 == 3) ? 0 : cur + 1;
    }
    psum += __shfl_xor(psum, 16);
    psum += __shfl_xor(psum, 32);
    if (lane < 16) sred[qt][phw][li] = psum;
    __syncthreads();
    if (phw == 0 && lane < 16) {
        float s = sred[qt][0][li] + sred[qt][1][li];
        sums[((size_t)ph0 * 8 + bd) * 4096 + q0 + qt * 16 + li] = s;
    }
#undef STAGE_K
}

// ---- B2 plan A: single-pass 256x256 tile, 8 waves (wave 128c x 64q), BK=32,
//      ring-4 counted-vmcnt, conflict-free 64B-row swizzle ((row>>1)&3)<<4. 1 block/CU. ----
template<int FUSEH>
__global__ __launch_bounds__(512, 2) void k_pv8(
        const u16* __restrict__ Lb, const u16* __restrict__ Rb,
        const u16* __restrict__ P, const float* __restrict__ sums,
        const u16* __restrict__ web, const float* __restrict__ hinvArr,
        float* __restrict__ out) {
    __shared__ u16 Vl[4][8192];    // ring: 256 c-rows x 32p (64B rows) = 16KB/set
    __shared__ u16 Pl[4][8192];    // ring: 256 q-rows x 32p
    int bd = (int)blockIdx.x & 7;            // XCD pin by bd
    int idx = (int)blockIdx.x >> 3;
    int mt = idx & 1, nt = idx >> 1;         // 2 x 16
    int dir = bd & 1, b = bd >> 1, osb = dir * 4 + b;
    const u16* V = (dir ? Lb : Rb) + (size_t)b * 512 * 4096;
    const u16* Pbd = P + ((size_t)bd << 24);
    int c0 = mt * 256, q0 = nt * 256;
    int tid = threadIdx.x;
    int wv = __builtin_amdgcn_readfirstlane(tid >> 6);
    int lane = tid & 63, g = lane >> 4, li = lane & 15;
    int wr = wv >> 2, wc = wv & 3;           // 2M x 4N; wave tile 128c x 64q

    // ---- staging sources (2 V-loads + 2 P-loads per thread per set) ----
    const u16 *vs0, *vs1, *pb0, *pb1;
    int pOff0a, pOff0b, pOff1a, pOff1b;
    {
        int o = tid * 16;                    // l=0
        int row = o >> 6, w = o & 63;
        int sw = ((row >> 1) & 3) << 4;
        int wd = w ^ sw;
        vs0 = V + (size_t)(c0 + row) * 4096 + (wd >> 1);
        int q = q0 + row, qtile = q >> 6, qr = q & 63;
        pb0 = Pbd + (size_t)(qtile * 64) * 4096 + qr * 64;
        pOff0a = ((wd) ^ ((qr & 7) << 4)) >> 1;
        pOff0b = ((64 + wd) ^ ((qr & 7) << 4)) >> 1;
    }
    {
        int o = 8192 + tid * 16;             // l=1
        int row = o >> 6, w = o & 63;
        int sw = ((row >> 1) & 3) << 4;
        int wd = w ^ sw;
        vs1 = V + (size_t)(c0 + row) * 4096 + (wd >> 1);
        int q = q0 + row, qtile = q >> 6, qr = q & 63;
        pb1 = Pbd + (size_t)(qtile * 64) * 4096 + qr * 64;
        pOff1a = ((wd) ^ ((qr & 7) << 4)) >> 1;
        pOff1b = ((64 + wd) ^ ((qr & 7) << 4)) >> 1;
    }

#define STAGE8(SLOT, T)                                                                    \
    {                                                                                      \
        gload_lds16(vs0 + (T) * 32, &Vl[SLOT][tid * 8]);                                   \
        gload_lds16(vs1 + (T) * 32, &Vl[SLOT][4096 + tid * 8]);                            \
        gload_lds16(pb0 + ((T) >> 1) * 4096 + (((T) & 1) ? pOff0b : pOff0a),               \
                    &Pl[SLOT][tid * 8]);                                                   \
        gload_lds16(pb1 + ((T) >> 1) * 4096 + (((T) & 1) ? pOff1b : pOff1a),               \
                    &Pl[SLOT][4096 + tid * 8]);                                            \
    }

    // ---- loop-invariant LDS read offsets ----
    unsigned aoff[8], boff[4];
#pragma unroll
    for (int mi = 0; mi < 8; mi++) {
        int row = wr * 128 + mi * 16 + li;
        aoff[mi] = (unsigned)row * 64 + (((unsigned)(g * 16)) ^ (((row >> 1) & 3) << 4));
    }
#pragma unroll
    for (int ni = 0; ni < 4; ni++) {
        int row = wc * 64 + ni * 16 + li;
        boff[ni] = (unsigned)row * 64 + (((unsigned)(g * 16)) ^ (((row >> 1) & 3) << 4));
    }

    f32x4 acc[8][4];
#pragma unroll
    for (int i = 0; i < 8; i++)
#pragma unroll
        for (int j = 0; j < 4; j++) acc[i][j] = (f32x4){0.f, 0.f, 0.f, 0.f};

    STAGE8(0, 0)
    STAGE8(1, 1)
    STAGE8(2, 2)

    for (int t = 0; t < 128; t++) {
        if (t < 126)       asm volatile("s_waitcnt vmcnt(8) lgkmcnt(0)\n\ts_barrier" ::: "memory");
        else if (t == 126) asm volatile("s_waitcnt vmcnt(4) lgkmcnt(0)\n\ts_barrier" ::: "memory");
        else               asm volatile("s_waitcnt vmcnt(0) lgkmcnt(0)\n\ts_barrier" ::: "memory");
        if (t < 125) {
            int slot = (t + 3) & 3;
            STAGE8(slot, t + 3)
        }
        int cur = t & 3;
        bf16x8 af[8], bf[4];
#pragma unroll
        for (int mi = 0; mi < 8; mi++)
            af[mi] = *reinterpret_cast<const bf16x8*>((char*)Vl[cur] + aoff[mi]);
#pragma unroll
        for (int ni = 0; ni < 4; ni++)
            bf[ni] = *reinterpret_cast<const bf16x8*>((char*)Pl[cur] + boff[ni]);
        __builtin_amdgcn_s_setprio(1);
#pragma unroll
        for (int mi = 0; mi < 8; mi++)
#pragma unroll
            for (int ni = 0; ni < 4; ni++)
                acc[mi][ni] = __builtin_amdgcn_mfma_f32_16x16x32_bf16(
                    af[mi], bf[ni], acc[mi][ni], 0, 0, 0);
        __builtin_amdgcn_s_setprio(0);
    }

    float* obase = out + ((size_t)osb * 1024 + 512) * 4096;
    const u16* wb = web + (size_t)osb * 512 * 4096;
#pragma unroll
    for (int ni = 0; ni < 4; ni++) {
        int q = q0 + wc * 64 + ni * 16 + li;
        float s0 = sums[(size_t)bd * 4096 + q];
        float s1 = sums[((size_t)8 + bd) * 4096 + q];
        float linv = 1.0f / (s0 + s1);
        float hinv = 0.f;
        if (FUSEH) hinv = hinvArr[(size_t)osb * 4096 + q];
#pragma unroll
        for (int mi = 0; mi < 8; mi++) {
            int c = c0 + wr * 128 + mi * 16 + g * 4;
#pragma unroll
            for (int r = 0; r < 4; r++) {
                float v = acc[mi][ni][r] * linv;
                if (FUSEH) v += bf2f(wb[(size_t)(c + r) * 4096 + q]) * hinv;
                obase[(size_t)(c + r) * 4096 + q] = v;
            }
        }
    }
#undef STAGE8
}

// ---- B2 plan B (round-8 proven): 128x128, dbuf 64KB, 2 blocks/CU, XCD-pinned ----
template<int FUSEH>
__global__ __launch_bounds__(256, 2) void k_pvC(
        const u16* __restrict__ Lb, const u16* __restrict__ Rb,
        const u16* __restrict__ P, const float* __restrict__ sums,
        const u16* __restrict__ web, const float* __restrict__ hinvArr,
        float* __restrict__ out, int bd0, int bdMask, int bdShift) {
    __shared__ u16 Tl[2][2][8192];
    int bdl, idx;
    if (bdMask == 3) {
        int xcd = (int)blockIdx.x & 7;
        bdl = xcd >> 1;
        idx = (((int)blockIdx.x >> 3) << 1) | (xcd & 1);
    } else {
        bdl = (int)blockIdx.x & bdMask;
        idx = (int)blockIdx.x >> bdShift;
    }
    int mtile = idx & 3;
    int ntile = idx >> 2;
    int bd = bd0 + bdl, dir = bd & 1, b = bd >> 1;
    int osb = dir * 4 + b;
    const u16* V = (dir ? Lb : Rb) + (size_t)b * 512 * 4096;
    const u16* Pbd = P + ((size_t)bdl << 24);
    int q0 = ntile * 128, c0 = mtile * 128, qt0 = ntile * 2;
    int tid = threadIdx.x;
    int wv = __builtin_amdgcn_readfirstlane(tid >> 6);
    int lane = tid & 63, g = lane >> 4, li = lane & 15;
    int wr = wv >> 1, wc = wv & 1;

#define STAGE_PV(BUF, T)                                                                   \
    {                                                                                      \
        _Pragma("unroll") for (int r0 = 0; r0 < 4; r0++) {                                 \
            int o = r0 * 4096 + tid * 16;                                                  \
            int row = o >> 7, w = o & 127;                                                 \
            int sw = (w ^ ((row & 7) << 4)) >> 1;                                          \
            gload_lds16(V + (((size_t)(c0 + row)) << 12) + (T) * 64 + sw,                  \
                        &Tl[BUF][0][r0 * 2048 + wv * 512]);                                \
            gload_lds16(Pbd + (((size_t)((qt0 + (r0 >> 1)) * 64 + (T))) << 12) +           \
                            (r0 & 1) * 2048 + tid * 8,                                     \
                        &Tl[BUF][1][r0 * 2048 + wv * 512]);                                \
        }                                                                                  \
    }

    f32x4 acc[4][4];
#pragma unroll
    for (int i = 0; i < 4; i++)
#pragma unroll
        for (int j = 0; j < 4; j++) acc[i][j] = (f32x4){0.f, 0.f, 0.f, 0.f};

    STAGE_PV(0, 0)

    for (int t = 0; t < 64; t++) {
        asm volatile("s_waitcnt vmcnt(0) lgkmcnt(0)\n\ts_barrier" ::: "memory");
        if (t < 63) STAGE_PV((t + 1) & 1, t + 1)
        int buf = t & 1;
        bf16x8 af[4][2], bf[4][2];
#pragma unroll
        for (int mi = 0; mi < 4; mi++) {
            int row = wr * 64 + mi * 16 + li;
            unsigned rb = (unsigned)row * 128, sz = (unsigned)((row & 7) << 4);
#pragma unroll
            for (int kk = 0; kk < 2; kk++)
                af[mi][kk] = *reinterpret_cast<const bf16x8*>(
                    (char*)Tl[buf][0] + rb + (((unsigned)(kk * 64 + g * 16)) ^ sz));
        }
#pragma unroll
        for (int ni = 0; ni < 4; ni++) {
            int row = wc * 64 + ni * 16 + li;
            unsigned rb = (unsigned)row * 128, sz = (unsigned)((row & 7) << 4);
#pragma unroll
            for (int kk = 0; kk < 2; kk++)
                bf[ni][kk] = *reinterpret_cast<const bf16x8*>(
                    (char*)Tl[buf][1] + rb + (((unsigned)(kk * 64 + g * 16)) ^ sz));
        }
        __builtin_amdgcn_s_setprio(1);
#pragma unroll
        for (int kk = 0; kk < 2; kk++)
#pragma unroll
            for (int mi = 0; mi < 4; mi++)
#pragma unroll
                for (int ni = 0; ni < 4; ni++)
                    acc[mi][ni] = __builtin_amdgcn_mfma_f32_16x16x32_bf16(
                        af[mi][kk], bf[ni][kk], acc[mi][ni], 0, 0, 0);
        __builtin_amdgcn_s_setprio(0);
    }

    float* obase = out + ((size_t)osb * 1024 + 512) * 4096;
    const u16* wb = web + (size_t)osb * 512 * 4096;
#pragma unroll
    for (int ni = 0; ni < 4; ni++) {
        int q = q0 + wc * 64 + ni * 16 + li;
        float s0 = sums[(size_t)bd * 4096 + q];
        float s1 = sums[((size_t)8 + bd) * 4096 + q];
        float linv = 1.0f / (s0 + s1);
        float hinv = 0.f;
        if (FUSEH) hinv = hinvArr[(size_t)osb * 4096 + q];
#pragma unroll
        for (int mi = 0; mi < 4; mi++) {
            int c = c0 + wr * 64 + mi * 16 + g * 4;
#pragma unroll
            for (int r = 0; r < 4; r++) {
                float v = acc[mi][ni][r] * linv;
                if (FUSEH) v += bf2f(wb[(size_t)(c + r) * 4096 + q]) * hinv;
                obase[(size_t)(c + r) * 4096 + q] = v;
            }
        }
    }
#undef STAGE_PV
}

// ---------------- D (fallback): homo softmax term, float4, 2-pass ----------------
__global__ __launch_bounds__(256) void k_homo(const float* __restrict__ L,
                                              const float* __restrict__ R,
                                              float* __restrict__ out) {
    __shared__ float4 red[16][16];
    int sb = blockIdx.x & 7, pblk = blockIdx.x >> 3;
    int side = sb & 1, b = sb >> 1;
    const float* src = (side ? R : L) + (long)b * 1024 * 4096;
    float* o = out + (long)(side * 4 + b) * 1024 * 4096;
    int p4 = threadIdx.x & 15, cg = threadIdx.x >> 4;
    int p = pblk * 64 + p4 * 4;
    const float* qo = src + p;
    const float* qt = src + (long)512 * 4096 + p;
    float4 sm = {0.f, 0.f, 0.f, 0.f};
    for (int c = cg * 32; c < cg * 32 + 32; c++) {
        float4 a = *reinterpret_cast<const float4*>(qo + (long)c * 4096);
        float4 t = *reinterpret_cast<const float4*>(qt + (long)c * 4096);
        sm.x += exp2f((a.x - t.x) * LOG2E);
        sm.y += exp2f((a.y - t.y) * LOG2E);
        sm.z += exp2f((a.z - t.z) * LOG2E);
        sm.w += exp2f((a.w - t.w) * LOG2E);
    }
    red[cg][p4] = sm;
    __syncthreads();
    float4 tot = {0.f, 0.f, 0.f, 0.f};
#pragma unroll
    for (int gR = 0; gR < 16; gR++) {
        float4 v = red[gR][p4];
        tot.x += v.x; tot.y += v.y; tot.z += v.z; tot.w += v.w;
    }
    float4 rinv = {1.0f / tot.x, 1.0f / tot.y, 1.0f / tot.z, 1.0f / tot.w};
    for (int c = cg * 32; c < cg * 32 + 32; c++) {
        float4 a = *reinterpret_cast<const float4*>(qo + (long)c * 4096);
        float4 t = *reinterpret_cast<const float4*>(qt + (long)c * 4096);
        float4* op = reinterpret_cast<float4*>(o + (long)(512 + c) * 4096 + p);
        float4 cur = *op;
        cur.x += t.x * exp2f((a.x - t.x) * LOG2E) * rinv.x;
        cur.y += t.y * exp2f((a.y - t.y) * LOG2E) * rinv.y;
        cur.z += t.z * exp2f((a.z - t.z) * LOG2E) * rinv.z;
        cur.w += t.w * exp2f((a.w - t.w) * LOG2E) * rinv.w;
        *op = cur;
    }
}

extern "C" void kernel_launch(void* const* d_in, const int* in_sizes, int n_in,
                              void* d_out, int out_size, void* d_ws, size_t ws_size,
                              hipStream_t stream) {
    const float* L  = (const float*)d_in[0];
    const float* R  = (const float*)d_in[1];
    const float* Wq = (const float*)d_in[2];
    const float* bq = (const float*)d_in[3];
    const float* Wk = (const float*)d_in[4];
    const float* bk = (const float*)d_in[5];
    float* out = (float*)d_out;
    char* ws = (char*)d_ws;

    size_t off = 0;
    u16* Wbq = (u16*)(ws + off); off += (size_t)128 * 512 * 2;
    u16* Wbk = (u16*)(ws + off); off += (size_t)128 * 512 * 2;
    u16* QL = (u16*)(ws + off); off += (size_t)NB * 4096 * 128 * 2;
    u16* KL = (u16*)(ws + off); off += (size_t)NB * 4096 * 128 * 2;
    u16* QR = (u16*)(ws + off); off += (size_t)NB * 4096 * 128 * 2;
    u16* KR = (u16*)(ws + off); off += (size_t)NB * 4096 * 128 * 2;
    u16* Lb = (u16*)(ws + off); off += (size_t)NB * 512 * 4096 * 2;
    u16* Rb = (u16*)(ws + off); off += (size_t)NB * 512 * 4096 * 2;
    float* sums = (float*)(ws + off); off += (size_t)2 * 8 * 4096 * 4;
    float* hinv = (float*)(ws + off); off += (size_t)8 * 4096 * 4;
    size_t off_nofuse = off;
    float* sumsH = (float*)(ws + off); off += (size_t)64 * 8 * 4096 * 4;
    u16* web = (u16*)(ws + off); off += (size_t)8 * 512 * 4096 * 2;
    off = (off + 255) & ~(size_t)255;
    size_t pchunk4 = (size_t)4 * 4096 * 4096 * 2;
    size_t pfull   = (size_t)8 * 4096 * 4096 * 2;

    k_wcvt <<<64, 1024, 0, stream>>>(Wq, Wk, Wbq, Wbk);

    if (ws_size >= off + pfull) {
        // ---- plan A: single-pass, 256-block k_pv8 ----
        u16* Pb = (u16*)(ws + off);
        k_cvtf   <<<2048, 256, 0, stream>>>(L, R, Lb, Rb, web, sumsH, out);
        k_hsum   <<<32,   256, 0, stream>>>(sumsH, hinv);
        k_proj   <<<1024, 256, 0, stream>>>(Lb, Rb, Wbq, Wbk, bq, bk, QL, KL, QR, KR);
        k_qk     <<<1024, 512, 0, stream>>>(QL, KL, QR, KR, Pb, sums, 0, 7, 3);
        k_pv8<1> <<<256,  512, 0, stream>>>(Lb, Rb, Pb, sums, web, hinv, out);
    } else if (ws_size >= off + pchunk4) {
        // ---- plan B: round-8 proven chunked path ----
        u16* Pb = (u16*)(ws + off);
        k_cvtf <<<2048, 256, 0, stream>>>(L, R, Lb, Rb, web, sumsH, out);
        k_hsum <<<32,   256, 0, stream>>>(sumsH, hinv);
        k_proj <<<1024, 256, 0, stream>>>(Lb, Rb, Wbq, Wbk, bq, bk, QL, KL, QR, KR);
        for (int c = 0; c < 2; c++) {
            k_qk     <<<512, 512, 0, stream>>>(QL, KL, QR, KR, Pb, sums, c * 4, 3, 2);
            k_pvC<1> <<<512, 256, 0, stream>>>(Lb, Rb, Pb, sums, web, hinv, out, c * 4, 3, 2);
        }
    } else {
        // ---- ultra-fallback: separate homo kernel, 1bd chunks ----
        size_t poff = (off_nofuse + 255) & ~(size_t)255;
        u16* Pb = (u16*)(ws + poff);
        k_cvt  <<<16384, 256, 0, stream>>>(L, R, Lb, Rb, out);
        k_proj <<<1024,  256, 0, stream>>>(Lb, Rb, Wbq, Wbk, bq, bk, QL, KL, QR, KR);
        for (int c = 0; c < 8; c++) {
            k_qk     <<<128, 512, 0, stream>>>(QL, KL, QR, KR, Pb, sums, c, 0, 0);
            k_pvC<0> <<<128, 256, 0, stream>>>(Lb, Rb, Pb, sums, web, hinv, out, c, 0, 0);
        }
        k_homo <<<512, 256, 0, stream>>>(L, R, out);
    }
}

// Round 11
// 381.371 us; speedup vs baseline: 1.2157x; 1.2157x over previous
//
#include <hip/hip_runtime.h>
#include <hip/hip_bf16.h>

// (B, C2, H, W) = (4, 1024, 64, 64); CH=512, HID=128, P=4096
#define NB 4
#define LOG2E 1.4426950408889634f

typedef unsigned short u16;
typedef __attribute__((ext_vector_type(8))) short bf16x8;
typedef __attribute__((ext_vector_type(4))) float f32x4;

static __device__ __forceinline__ float bf2f(u16 u) {
    union { float f; unsigned v; } x; x.v = ((unsigned)u) << 16; return x.f;
}
static __device__ __forceinline__ u16 f2bf(float f) {
    unsigned v = __builtin_bit_cast(unsigned, f);
    return (u16)((v + 0x7FFFu + ((v >> 16) & 1u)) >> 16);
}
static __device__ __forceinline__ void gload_lds16(const u16* g, u16* l) {
    __builtin_amdgcn_global_load_lds(
        (const __attribute__((address_space(1))) unsigned*)(const void*)g,
        (__attribute__((address_space(3))) unsigned*)(void*)l, 16, 0, 0);
}

// ---------------- A0: W f32 -> bf16 ----------------
__global__ void k_wcvt(const float* __restrict__ Wq, const float* __restrict__ Wk,
                       u16* __restrict__ Wbq, u16* __restrict__ Wbk) {
    int i = blockIdx.x * 1024 + threadIdx.x;   // 65536
    Wbq[i] = f2bf(Wq[i]);
    Wbk[i] = f2bf(Wk[i]);
}

// ---- A1-fused: contiguous-p layout. Block = (sb, pseg of 1024p, cpart of 8ch). ----
__global__ __launch_bounds__(256) void k_cvtf(
        const float* __restrict__ L, const float* __restrict__ R,
        u16* __restrict__ Lb, u16* __restrict__ Rb,
        u16* __restrict__ web, float* __restrict__ sumsH, float* __restrict__ out) {
    __shared__ float pred[4][1024];
    int idx = blockIdx.x;
    int sb = idx & 7, pseg = (idx >> 3) & 3, cpart = idx >> 5;   // 8 x 4 x 64
    int side = sb & 1, b = sb >> 1;
    int osb = side * 4 + b;
    const float* src = (side ? R : L) + (size_t)b * 1024 * 4096;
    u16* lbbase = (side ? Rb : Lb) + (size_t)b * 512 * 4096;
    int tid = threadIdx.x, wv = tid >> 6, lane = tid & 63;
    int p0 = pseg * 1024;
    int cA = cpart * 8 + wv * 2;
#pragma unroll
    for (int s = 0; s < 4; s++) {
        int p = p0 + s * 256 + lane * 4;
        float4 sm = {0.f, 0.f, 0.f, 0.f};
#pragma unroll
        for (int cc = 0; cc < 2; cc++) {
            int c = cA + cc;
            float4 a = *reinterpret_cast<const float4*>(src + (size_t)c * 4096 + p);
            float4 t = *reinterpret_cast<const float4*>(src + (size_t)(512 + c) * 4096 + p);
            ushort4 ub;
            ub.x = f2bf(a.x); ub.y = f2bf(a.y); ub.z = f2bf(a.z); ub.w = f2bf(a.w);
            *reinterpret_cast<ushort4*>(lbbase + (size_t)c * 4096 + p) = ub;
            *reinterpret_cast<float4*>(out + ((size_t)osb * 1024 + c) * 4096 + p) = a;
            float4 e;
            e.x = exp2f((a.x - t.x) * LOG2E);
            e.y = exp2f((a.y - t.y) * LOG2E);
            e.z = exp2f((a.z - t.z) * LOG2E);
            e.w = exp2f((a.w - t.w) * LOG2E);
            sm.x += e.x; sm.y += e.y; sm.z += e.z; sm.w += e.w;
            ushort4 wb_;
            wb_.x = f2bf(t.x * e.x); wb_.y = f2bf(t.y * e.y);
            wb_.z = f2bf(t.z * e.z); wb_.w = f2bf(t.w * e.w);
            *reinterpret_cast<ushort4*>(web + ((size_t)osb * 512 + c) * 4096 + p) = wb_;
        }
        *reinterpret_cast<float4*>(&pred[wv][s * 256 + lane * 4]) = sm;
    }
    __syncthreads();
    {
        float4 t0 = *reinterpret_cast<const float4*>(&pred[0][tid * 4]);
        float4 t1 = *reinterpret_cast<const float4*>(&pred[1][tid * 4]);
        float4 t2 = *reinterpret_cast<const float4*>(&pred[2][tid * 4]);
        float4 t3 = *reinterpret_cast<const float4*>(&pred[3][tid * 4]);
        float4 tot;
        tot.x = (t0.x + t1.x) + (t2.x + t3.x);
        tot.y = (t0.y + t1.y) + (t2.y + t3.y);
        tot.z = (t0.z + t1.z) + (t2.z + t3.z);
        tot.w = (t0.w + t1.w) + (t2.w + t3.w);
        *reinterpret_cast<float4*>(
            sumsH + ((size_t)cpart * 8 + osb) * 4096 + p0 + tid * 4) = tot;
    }
}

// ---- A1b: reduce 64 channel-part sums -> hinv = 1/sum ----
__global__ __launch_bounds__(256) void k_hsum(const float* __restrict__ sumsH,
                                              float* __restrict__ hinv) {
    int i = blockIdx.x * 256 + threadIdx.x;
    float4 tot = {0.f, 0.f, 0.f, 0.f};
    for (int cp = 0; cp < 64; cp++) {
        float4 v = *reinterpret_cast<const float4*>(sumsH + (size_t)cp * 8 * 4096 + (size_t)i * 4);
        tot.x += v.x; tot.y += v.y; tot.z += v.z; tot.w += v.w;
    }
    float4 r = {1.0f / tot.x, 1.0f / tot.y, 1.0f / tot.z, 1.0f / tot.w};
    *reinterpret_cast<float4*>(hinv + (size_t)i * 4) = r;
}

// ------- A1 (fallback): f32 -> bf16 convert; copy q_orig -------
__global__ void k_cvt(const float* __restrict__ L, const float* __restrict__ R,
                      u16* __restrict__ Lb, u16* __restrict__ Rb, float* __restrict__ out) {
    int i = blockIdx.x * 256 + threadIdx.x;
    int pq = i & 1023;
    int c = (i >> 10) & 511;
    int b = (i >> 19) & 3;
    int side = i >> 21;
    const float* src = (side ? R : L) + ((long)(b * 1024 + c) << 12) + (pq << 2);
    float4 v = *reinterpret_cast<const float4*>(src);
    ushort4 u;
    u.x = f2bf(v.x); u.y = f2bf(v.y); u.z = f2bf(v.z); u.w = f2bf(v.w);
    *reinterpret_cast<ushort4*>((side ? Rb : Lb) + ((long)(b * 512 + c) << 12) + (pq << 2)) = u;
    *reinterpret_cast<float4*>(out + ((long)(side * 4 + b) * 1024 + c) * 4096 + (pq << 2)) = v;
}

// ---------------- A2: projections via MFMA. Out: pos-major bf16 [p][128] ----------------
__global__ __launch_bounds__(256) void k_proj(
        const u16* __restrict__ Lb, const u16* __restrict__ Rb,
        const u16* __restrict__ Wbq, const u16* __restrict__ Wbk,
        const float* __restrict__ bq, const float* __restrict__ bk,
        u16* __restrict__ QL, u16* __restrict__ KL,
        u16* __restrict__ QR, u16* __restrict__ KR) {
    __shared__ u16 XT[2][64 * 40];
    int pj = blockIdx.x & 15, pt = blockIdx.x >> 4;
    int ty = pj >> 2, b = pj & 3;
    const u16* src; const u16* Wb; const float* bias; u16* dst;
    if (ty == 0)      { src = Lb; Wb = Wbq; bias = bq; dst = QL; }
    else if (ty == 1) { src = Rb; Wb = Wbk; bias = bk; dst = KL; }
    else if (ty == 2) { src = Rb; Wb = Wbq; bias = bq; dst = QR; }
    else              { src = Lb; Wb = Wbk; bias = bk; dst = KR; }
    const u16* X = src + (long)b * 512 * 4096 + pt * 64;
    int tid = threadIdx.x;
    int wv = __builtin_amdgcn_readfirstlane(tid >> 6);
    int lane = tid & 63, g = lane >> 4, li = lane & 15;

    f32x4 acc[8];
#pragma unroll
    for (int ob = 0; ob < 8; ob++)
#pragma unroll
        for (int r = 0; r < 4; r++) acc[ob][r] = bias[ob * 16 + g * 4 + r];

    int c_r = tid >> 3, j = tid & 7;
    bf16x8 gx = *reinterpret_cast<const bf16x8*>(X + (long)c_r * 4096 + j * 8);
#pragma unroll
    for (int k = 0; k < 8; k++) XT[0][(j * 8 + k) * 40 + c_r] = (u16)gx[k];
    __syncthreads();

    for (int cc = 0; cc < 16; cc++) {
        int buf = cc & 1;
        bf16x8 gn;
        if (cc < 15)
            gn = *reinterpret_cast<const bf16x8*>(X + (long)(cc * 32 + 32 + c_r) * 4096 + j * 8);
        bf16x8 xb = *reinterpret_cast<const bf16x8*>(&XT[buf][(wv * 16 + li) * 40 + g * 8]);
#pragma unroll
        for (int ob = 0; ob < 8; ob++) {
            bf16x8 aw = *reinterpret_cast<const bf16x8*>(Wb + (long)(ob * 16 + li) * 512 + cc * 32 + g * 8);
            acc[ob] = __builtin_amdgcn_mfma_f32_16x16x32_bf16(aw, xb, acc[ob], 0, 0, 0);
        }
        if (cc < 15) {
#pragma unroll
            for (int k = 0; k < 8; k++) XT[buf ^ 1][(j * 8 + k) * 40 + c_r] = (u16)gn[k];
        }
        __syncthreads();
    }
    u16* d = dst + ((long)b * 4096 + pt * 64 + wv * 16 + li) * 128;
#pragma unroll
    for (int ob = 0; ob < 8; ob++) {
        uint2 w;
        w.x = (unsigned)f2bf(acc[ob][0]) | ((unsigned)f2bf(acc[ob][1]) << 16);
        w.y = (unsigned)f2bf(acc[ob][2]) | ((unsigned)f2bf(acc[ob][3]) << 16);
        *reinterpret_cast<uint2*>(d + ob * 16 + g * 4) = w;
    }
}

// ---- B1: P = exp(Q.K^T), 8KB tiles [qtile][ptile][64q][64p-swz].
//      p-split x4; dbuf + vmcnt(1) (FIFO-retire audit: queue [L(t)a,L(t)b,S(t-1)]);
//      LDS exactly 40960B (sred aliased into Ps) -> 4 blocks/CU. ----
__global__ __launch_bounds__(512, 8) void k_qk(
        const u16* __restrict__ QL, const u16* __restrict__ KL,
        const u16* __restrict__ QR, const u16* __restrict__ KR,
        u16* __restrict__ P, float* __restrict__ sums,
        int bd0, int nbdLog2) {
    __shared__ u16 Kl[2][8192];       // [64p][128c] 16KB each, byte^=(p&7)<<4
    __shared__ u16 Ps[4096];          // [64q][64p] 8KB, byte^=(q&7)<<4; tail-reused as sred
    int blk = (int)blockIdx.x;
    int bdl = blk & ((1 << nbdLog2) - 1);
    int rest = blk >> nbdLog2;
    int ph0 = rest & 3;               // p-quarter: tiles [ph0*16, ph0*16+16)
    int qtile = rest >> 2;            // 0..63
    int bd = bd0 + bdl, dir = bd & 1, b = bd >> 1;
    const u16* Qt = (dir ? QR : QL) + (size_t)b * 4096 * 128;
    const u16* Kt = (dir ? KR : KL) + (size_t)b * 4096 * 128;
    u16* Pbd = P + ((size_t)bdl << 24);
    int q0 = qtile * 64;
    int tid = threadIdx.x;
    int wv = __builtin_amdgcn_readfirstlane(tid >> 6);
    int lane = tid & 63, g = lane >> 4, li = lane & 15;
    int qt = wv >> 1, phw = wv & 1;

#define STAGE_K(BUF, PT)                                                                   \
    {                                                                                      \
        _Pragma("unroll") for (int r0 = 0; r0 < 2; r0++) {                                 \
            int o = r0 * 8192 + tid * 16;                                                  \
            int row = o >> 8, w = o & 255;                                                 \
            int sw = (w ^ ((row & 7) << 4)) >> 1;                                          \
            gload_lds16(Kt + (((size_t)((PT) * 64 + row)) << 7) + sw,                      \
                        &Kl[BUF][r0 * 4096 + wv * 512]);                                   \
        }                                                                                  \
    }

    bf16x8 qf[4];
#pragma unroll
    for (int hc = 0; hc < 4; hc++)
        qf[hc] = *reinterpret_cast<const bf16x8*>(
            Qt + (size_t)(q0 + qt * 16 + li) * 128 + hc * 32 + g * 8);
    float psum = 0.f;
    STAGE_K(0, ph0 * 16)

    for (int tt = 0; tt < 16; tt++) {
        int pt = ph0 * 16 + tt;
        if (tt == 0) asm volatile("s_waitcnt vmcnt(0) lgkmcnt(0)\n\ts_barrier" ::: "memory");
        else         asm volatile("s_waitcnt vmcnt(1) lgkmcnt(0)\n\ts_barrier" ::: "memory");
        if (tt < 15) STAGE_K((tt + 1) & 1, pt + 1)
        int buf = tt & 1;
        f32x4 sv[2];
        sv[0] = (f32x4){0.f, 0.f, 0.f, 0.f};
        sv[1] = (f32x4){0.f, 0.f, 0.f, 0.f};
        __builtin_amdgcn_s_setprio(1);
#pragma unroll
        for (int ps = 0; ps < 2; ps++) {
            int row = phw * 32 + ps * 16 + li;
            unsigned rb = (unsigned)row * 256;
            unsigned sz = (unsigned)((row & 7) << 4);
#pragma unroll
            for (int hc = 0; hc < 4; hc++) {
                bf16x8 kf = *reinterpret_cast<const bf16x8*>(
                    (char*)Kl[buf] + rb + (((unsigned)(hc * 64 + g * 16)) ^ sz));
                sv[ps] = __builtin_amdgcn_mfma_f32_16x16x32_bf16(kf, qf[hc], sv[ps], 0, 0, 0);
            }
        }
        __builtin_amdgcn_s_setprio(0);
        int qrow = qt * 16 + li;
        unsigned qsz = (unsigned)((qrow & 7) << 4);
#pragma unroll
        for (int ps = 0; ps < 2; ps++) {
            float e0 = exp2f(sv[ps][0] * LOG2E);
            float e1 = exp2f(sv[ps][1] * LOG2E);
            float e2 = exp2f(sv[ps][2] * LOG2E);
            float e3 = exp2f(sv[ps][3] * LOG2E);
            psum += (e0 + e1) + (e2 + e3);
            uint2 pk;
            pk.x = (unsigned)f2bf(e0) | ((unsigned)f2bf(e1) << 16);
            pk.y = (unsigned)f2bf(e2) | ((unsigned)f2bf(e3) << 16);
            unsigned off = (unsigned)qrow * 128 +
                           (((unsigned)(phw * 64 + ps * 32 + g * 8)) ^ qsz);
            *reinterpret_cast<uint2*>((char*)Ps + off) = pk;
        }
        asm volatile("s_waitcnt lgkmcnt(0)\n\ts_barrier" ::: "memory");
        {
            uint4 d = *reinterpret_cast<const uint4*>((char*)Ps + tid * 16);
            *reinterpret_cast<uint4*>(
                Pbd + ((size_t)(qtile * 64 + pt) << 12) + tid * 8) = d;
        }
    }
    __syncthreads();                      // all Ps reads done -> safe to alias
    float (*sred)[2][16] = (float(*)[2][16])(void*)Ps;   // 512B inside Ps
    psum += __shfl_xor(psum, 16);
    psum += __shfl_xor(psum, 32);
    if (lane < 16) sred[qt][phw][li] = psum;
    __syncthreads();
    if (phw == 0 && lane < 16) {
        float s = sred[qt][0][li] + sred[qt][1][li];
        sums[((size_t)ph0 * 8 + bd) * 4096 + q0 + qt * 16 + li] = s;
    }
#undef STAGE_K
}

// ---- B2 (round-8 proven): 128x128, dbuf 64KB, 2 blocks/CU, XCD-pinned bd ----
template<int FUSEH>
__global__ __launch_bounds__(256, 2) void k_pvC(
        const u16* __restrict__ Lb, const u16* __restrict__ Rb,
        const u16* __restrict__ P, const float* __restrict__ sums,
        const u16* __restrict__ web, const float* __restrict__ hinvArr,
        float* __restrict__ out, int bd0, int bdMask, int bdShift) {
    __shared__ u16 Tl[2][2][8192];
    int bdl, idx;
    if (bdMask == 3) {
        int xcd = (int)blockIdx.x & 7;
        bdl = xcd >> 1;
        idx = (((int)blockIdx.x >> 3) << 1) | (xcd & 1);
    } else {
        bdl = (int)blockIdx.x & bdMask;
        idx = (int)blockIdx.x >> bdShift;
    }
    int mtile = idx & 3;
    int ntile = idx >> 2;
    int bd = bd0 + bdl, dir = bd & 1, b = bd >> 1;
    int osb = dir * 4 + b;
    const u16* V = (dir ? Lb : Rb) + (size_t)b * 512 * 4096;
    const u16* Pbd = P + ((size_t)bdl << 24);
    int q0 = ntile * 128, c0 = mtile * 128, qt0 = ntile * 2;
    int tid = threadIdx.x;
    int wv = __builtin_amdgcn_readfirstlane(tid >> 6);
    int lane = tid & 63, g = lane >> 4, li = lane & 15;
    int wr = wv >> 1, wc = wv & 1;

#define STAGE_PV(BUF, T)                                                                   \
    {                                                                                      \
        _Pragma("unroll") for (int r0 = 0; r0 < 4; r0++) {                                 \
            int o = r0 * 4096 + tid * 16;                                                  \
            int row = o >> 7, w = o & 127;                                                 \
            int sw = (w ^ ((row & 7) << 4)) >> 1;                                          \
            gload_lds16(V + (((size_t)(c0 + row)) << 12) + (T) * 64 + sw,                  \
                        &Tl[BUF][0][r0 * 2048 + wv * 512]);                                \
            gload_lds16(Pbd + (((size_t)((qt0 + (r0 >> 1)) * 64 + (T))) << 12) +           \
                            (r0 & 1) * 2048 + tid * 8,                                     \
                        &Tl[BUF][1][r0 * 2048 + wv * 512]);                                \
        }                                                                                  \
    }

    f32x4 acc[4][4];
#pragma unroll
    for (int i = 0; i < 4; i++)
#pragma unroll
        for (int j = 0; j < 4; j++) acc[i][j] = (f32x4){0.f, 0.f, 0.f, 0.f};

    STAGE_PV(0, 0)

    for (int t = 0; t < 64; t++) {
        asm volatile("s_waitcnt vmcnt(0) lgkmcnt(0)\n\ts_barrier" ::: "memory");
        if (t < 63) STAGE_PV((t + 1) & 1, t + 1)
        int buf = t & 1;
        bf16x8 af[4][2], bf[4][2];
#pragma unroll
        for (int mi = 0; mi < 4; mi++) {
            int row = wr * 64 + mi * 16 + li;
            unsigned rb = (unsigned)row * 128, sz = (unsigned)((row & 7) << 4);
#pragma unroll
            for (int kk = 0; kk < 2; kk++)
                af[mi][kk] = *reinterpret_cast<const bf16x8*>(
                    (char*)Tl[buf][0] + rb + (((unsigned)(kk * 64 + g * 16)) ^ sz));
        }
#pragma unroll
        for (int ni = 0; ni < 4; ni++) {
            int row = wc * 64 + ni * 16 + li;
            unsigned rb = (unsigned)row * 128, sz = (unsigned)((row & 7) << 4);
#pragma unroll
            for (int kk = 0; kk < 2; kk++)
                bf[ni][kk] = *reinterpret_cast<const bf16x8*>(
                    (char*)Tl[buf][1] + rb + (((unsigned)(kk * 64 + g * 16)) ^ sz));
        }
        __builtin_amdgcn_s_setprio(1);
#pragma unroll
        for (int kk = 0; kk < 2; kk++)
#pragma unroll
            for (int mi = 0; mi < 4; mi++)
#pragma unroll
                for (int ni = 0; ni < 4; ni++)
                    acc[mi][ni] = __builtin_amdgcn_mfma_f32_16x16x32_bf16(
                        af[mi][kk], bf[ni][kk], acc[mi][ni], 0, 0, 0);
        __builtin_amdgcn_s_setprio(0);
    }

    float* obase = out + ((size_t)osb * 1024 + 512) * 4096;
    const u16* wb = web + (size_t)osb * 512 * 4096;
#pragma unroll
    for (int ni = 0; ni < 4; ni++) {
        int q = q0 + wc * 64 + ni * 16 + li;
        float s = sums[(size_t)bd * 4096 + q] +
                  sums[((size_t)8 + bd) * 4096 + q] +
                  sums[((size_t)16 + bd) * 4096 + q] +
                  sums[((size_t)24 + bd) * 4096 + q];
        float linv = 1.0f / s;
        float hinv = 0.f;
        if (FUSEH) hinv = hinvArr[(size_t)osb * 4096 + q];
#pragma unroll
        for (int mi = 0; mi < 4; mi++) {
            int c = c0 + wr * 64 + mi * 16 + g * 4;
#pragma unroll
            for (int r = 0; r < 4; r++) {
                float v = acc[mi][ni][r] * linv;
                if (FUSEH) v += bf2f(wb[(size_t)(c + r) * 4096 + q]) * hinv;
                obase[(size_t)(c + r) * 4096 + q] = v;
            }
        }
    }
#undef STAGE_PV
}

// ---------------- D (fallback): homo softmax term, float4, 2-pass ----------------
__global__ __launch_bounds__(256) void k_homo(const float* __restrict__ L,
                                              const float* __restrict__ R,
                                              float* __restrict__ out) {
    __shared__ float4 red[16][16];
    int sb = blockIdx.x & 7, pblk = blockIdx.x >> 3;
    int side = sb & 1, b = sb >> 1;
    const float* src = (side ? R : L) + (long)b * 1024 * 4096;
    float* o = out + (long)(side * 4 + b) * 1024 * 4096;
    int p4 = threadIdx.x & 15, cg = threadIdx.x >> 4;
    int p = pblk * 64 + p4 * 4;
    const float* qo = src + p;
    const float* qt = src + (long)512 * 4096 + p;
    float4 sm = {0.f, 0.f, 0.f, 0.f};
    for (int c = cg * 32; c < cg * 32 + 32; c++) {
        float4 a = *reinterpret_cast<const float4*>(qo + (long)c * 4096);
        float4 t = *reinterpret_cast<const float4*>(qt + (long)c * 4096);
        sm.x += exp2f((a.x - t.x) * LOG2E);
        sm.y += exp2f((a.y - t.y) * LOG2E);
        sm.z += exp2f((a.z - t.z) * LOG2E);
        sm.w += exp2f((a.w - t.w) * LOG2E);
    }
    red[cg][p4] = sm;
    __syncthreads();
    float4 tot = {0.f, 0.f, 0.f, 0.f};
#pragma unroll
    for (int gR = 0; gR < 16; gR++) {
        float4 v = red[gR][p4];
        tot.x += v.x; tot.y += v.y; tot.z += v.z; tot.w += v.w;
    }
    float4 rinv = {1.0f / tot.x, 1.0f / tot.y, 1.0f / tot.z, 1.0f / tot.w};
    for (int c = cg * 32; c < cg * 32 + 32; c++) {
        float4 a = *reinterpret_cast<const float4*>(qo + (long)c * 4096);
        float4 t = *reinterpret_cast<const float4*>(qt + (long)c * 4096);
        float4* op = reinterpret_cast<float4*>(o + (long)(512 + c) * 4096 + p);
        float4 cur = *op;
        cur.x += t.x * exp2f((a.x - t.x) * LOG2E) * rinv.x;
        cur.y += t.y * exp2f((a.y - t.y) * LOG2E) * rinv.y;
        cur.z += t.z * exp2f((a.z - t.z) * LOG2E) * rinv.z;
        cur.w += t.w * exp2f((a.w - t.w) * LOG2E) * rinv.w;
        *op = cur;
    }
}

extern "C" void kernel_launch(void* const* d_in, const int* in_sizes, int n_in,
                              void* d_out, int out_size, void* d_ws, size_t ws_size,
                              hipStream_t stream) {
    const float* L  = (const float*)d_in[0];
    const float* R  = (const float*)d_in[1];
    const float* Wq = (const float*)d_in[2];
    const float* bq = (const float*)d_in[3];
    const float* Wk = (const float*)d_in[4];
    const float* bk = (const float*)d_in[5];
    float* out = (float*)d_out;
    char* ws = (char*)d_ws;

    size_t off = 0;
    u16* Wbq = (u16*)(ws + off); off += (size_t)128 * 512 * 2;
    u16* Wbk = (u16*)(ws + off); off += (size_t)128 * 512 * 2;
    u16* QL = (u16*)(ws + off); off += (size_t)NB * 4096 * 128 * 2;
    u16* KL = (u16*)(ws + off); off += (size_t)NB * 4096 * 128 * 2;
    u16* QR = (u16*)(ws + off); off += (size_t)NB * 4096 * 128 * 2;
    u16* KR = (u16*)(ws + off); off += (size_t)NB * 4096 * 128 * 2;
    u16* Lb = (u16*)(ws + off); off += (size_t)NB * 512 * 4096 * 2;
    u16* Rb = (u16*)(ws + off); off += (size_t)NB * 512 * 4096 * 2;
    float* sums = (float*)(ws + off); off += (size_t)4 * 8 * 4096 * 4;
    float* hinv = (float*)(ws + off); off += (size_t)8 * 4096 * 4;
    size_t off_nofuse = off;
    float* sumsH = (float*)(ws + off); off += (size_t)64 * 8 * 4096 * 4;
    u16* web = (u16*)(ws + off); off += (size_t)8 * 512 * 4096 * 2;
    off = (off + 255) & ~(size_t)255;
    size_t pchunk4 = (size_t)4 * 4096 * 4096 * 2;

    k_wcvt <<<64, 1024, 0, stream>>>(Wq, Wk, Wbq, Wbk);

    if (ws_size >= off + pchunk4) {
        // ---- fused-homo path, 4bd chunks ----
        u16* Pb = (u16*)(ws + off);
        k_cvtf <<<2048, 256, 0, stream>>>(L, R, Lb, Rb, web, sumsH, out);
        k_hsum <<<32,   256, 0, stream>>>(sumsH, hinv);
        k_proj <<<1024, 256, 0, stream>>>(Lb, Rb, Wbq, Wbk, bq, bk, QL, KL, QR, KR);
        for (int c = 0; c < 2; c++) {
            k_qk     <<<1024, 512, 0, stream>>>(QL, KL, QR, KR, Pb, sums, c * 4, 2);
            k_pvC<1> <<<512,  256, 0, stream>>>(Lb, Rb, Pb, sums, web, hinv, out, c * 4, 3, 2);
        }
    } else {
        // ---- fallback: separate homo kernel, 1bd chunks ----
        size_t poff = (off_nofuse + 255) & ~(size_t)255;
        u16* Pb = (u16*)(ws + poff);
        k_cvt  <<<16384, 256, 0, stream>>>(L, R, Lb, Rb, out);
        k_proj <<<1024,  256, 0, stream>>>(Lb, Rb, Wbq, Wbk, bq, bk, QL, KL, QR, KR);
        for (int c = 0; c < 8; c++) {
            k_qk     <<<256, 512, 0, stream>>>(QL, KL, QR, KR, Pb, sums, c, 0);
            k_pvC<0> <<<128, 256, 0, stream>>>(Lb, Rb, Pb, sums, web, hinv, out, c, 0, 0);
        }
        k_homo <<<512, 256, 0, stream>>>(L, R, out);
    }
}